// Round 4
// baseline (820.104 us; speedup 1.0000x reference)
//
#include <hip/hip_runtime.h>
#include <hip/hip_bf16.h>

#define BATCH 32
#define CHN   256
#define HWSZ  1024            // 32*32
#define NPIX  32768           // BATCH*HWSZ
#define NEMB  1024
#define NELEM 8388608         // BATCH*CHN*HWSZ
#define FLT_BIG 3.402823466e+38f
#define KCH   16              // K chunk per stage

// workspace layout (float offsets)
#define WS_CBT   0            // transposed codebook [256][1024]
#define WS_CNORM 262144       // 1024 floats
#define WS_XNORM 263168       // 32768 floats
#define WS_KEYS  296192       // 32768 u64 keys (65536 floats), byte off 1184768 (8B aligned)
#define WS_ACCUM 361728       // 1 double (byte 1446912, 8B aligned)

// output layout (float offsets)
#define OUT_U    0
#define OUT_ZT   8388608
#define OUT_LOSS 16777216
#define OUT_IDX  16777217

// async global->LDS, 16B per lane. LDS dest must be lane-linear (base + lane*16).
__device__ __forceinline__ void gld_lds16(const float* g, float* lds) {
    __builtin_amdgcn_global_load_lds(
        (const __attribute__((address_space(1))) void*)g,
        (__attribute__((address_space(3))) void*)lds, 16, 0, 0);
}

// ---------------- prep: cb transpose + cnorm | xnorm + keys init + accum ----------------
__global__ __launch_bounds__(256) void k_prep(const float* __restrict__ cb,
                                              const float* __restrict__ u,
                                              float* __restrict__ ws) {
    int bid = blockIdx.x;
    if (bid < NEMB) {
        int n = bid;                 // code id
        int c = threadIdx.x;         // channel
        float v = cb[(size_t)n * CHN + c];
        ws[WS_CBT + (size_t)c * NEMB + n] = v;
        float s = v * v;
        #pragma unroll
        for (int off = 32; off > 0; off >>= 1) s += __shfl_down(s, off, 64);
        __shared__ float ls[4];
        if ((threadIdx.x & 63) == 0) ls[threadIdx.x >> 6] = s;
        __syncthreads();
        if (threadIdx.x == 0) ws[WS_CNORM + n] = (ls[0] + ls[1]) + (ls[2] + ls[3]);
    } else {
        int pb  = bid - NEMB;        // 0..511
        int P0  = pb * 64;
        int b   = P0 >> 10;
        int hw0 = P0 & 1023;
        int lane = threadIdx.x & 63;
        int grp  = threadIdx.x >> 6; // channel quarter
        const float* up = u + (size_t)b * (CHN * HWSZ) + hw0 + lane;
        float s = 0.f;
        #pragma unroll 8
        for (int c = 0; c < 64; ++c) {
            float v = up[(size_t)(grp * 64 + c) * HWSZ];
            s = fmaf(v, v, s);
        }
        __shared__ float ls2[4][64];
        ls2[grp][lane] = s;
        __syncthreads();
        if (grp == 0)
            ws[WS_XNORM + P0 + lane] =
                (ls2[0][lane] + ls2[1][lane]) + (ls2[2][lane] + ls2[3][lane]);
        if (threadIdx.x < 64)
            ((unsigned long long*)(ws + WS_KEYS))[P0 + threadIdx.x] = ~0ULL;
        if (pb == 0 && threadIdx.x == 0) *(double*)&ws[WS_ACCUM] = 0.0;
    }
}

// ---------------- main: distance GEMM + argmin ----------------
// Grid 1024 = 256 pixel-blocks x 4 code-parts. Block: 256 thr, 128 pix x 256 codes,
// per-thread 16x8. K-chunk 16, double-buffered gld_lds staging. 48KB LDS -> 3 blk/CU.
// A-reads: thread tx reads pixel-quads {tx, tx+8, tx+16, tx+24} -> 8 distinct
// bank-groups per instr, conflict-free with linear (gld_lds-compatible) layout.
__global__ __launch_bounds__(256, 3) void k_argmin(const float* __restrict__ u,
                                                   const float* __restrict__ ws,
                                                   unsigned long long* __restrict__ keys) {
    __shared__ float s_u[2][KCH * 128];     // 16 KB  (slot16(k,p4) = k*32 + p4)
    __shared__ float s_cb[2][KCH * 256];    // 32 KB

    const float* cbT = ws + WS_CBT;
    int bid  = blockIdx.x;
    int pb   = bid >> 2;
    int part = bid & 3;
    int P0   = pb * 128;
    int b    = P0 >> 10;
    int hw0  = P0 & 1023;
    int tid  = threadIdx.x;
    int tx   = tid & 7;                 // pixel group
    int ty   = tid >> 3;                // code group (8 codes)
    int n0   = part * 256;
    const float* ub = u + (size_t)b * (CHN * HWSZ) + hw0;

    const int qa0 = tid, qa1 = tid + 256;

    auto stage = [&](int s, int buf) {
        int c0 = s * KCH;
        float* su  = &s_u[buf][0];
        float* scb = &s_cb[buf][0];
        // u chunk: 16k x 128 pix, 2 x 16B per thread, lane-linear dest
        gld_lds16(&ub[(size_t)(c0 + (qa0 >> 5)) * HWSZ + (qa0 & 31) * 4], &su[qa0 * 4]);
        gld_lds16(&ub[(size_t)(c0 + (qa1 >> 5)) * HWSZ + (qa1 & 31) * 4], &su[qa1 * 4]);
        // cb chunk: 16k x 256 codes, 4 x 16B per thread
        #pragma unroll
        for (int it = 0; it < 4; ++it) {
            int q = it * 256 + tid;
            gld_lds16(&cbT[(size_t)(c0 + (q >> 6)) * NEMB + n0 + (q & 63) * 4],
                      &scb[q * 4]);
        }
    };

    float acc[16][8];
    #pragma unroll
    for (int i = 0; i < 16; ++i)
        #pragma unroll
        for (int j = 0; j < 8; ++j) acc[i][j] = 0.f;

    stage(0, 0);

    for (int s = 0; s < 16; ++s) {
        int buf = s & 1;
        __syncthreads();                      // chunk s resident
        if (s < 15) stage(s + 1, buf ^ 1);    // prefetch next chunk
        const float* su  = &s_u[buf][0];
        const float* scb = &s_cb[buf][0];
        #pragma unroll
        for (int k = 0; k < KCH; ++k) {
            float4 t0 = *(const float4*)&su[(k * 32 + 0 * 8 + tx) * 4];
            float4 t1 = *(const float4*)&su[(k * 32 + 1 * 8 + tx) * 4];
            float4 t2 = *(const float4*)&su[(k * 32 + 2 * 8 + tx) * 4];
            float4 t3 = *(const float4*)&su[(k * 32 + 3 * 8 + tx) * 4];
            float4 b0 = *(const float4*)&scb[k * 256 + ty * 8];
            float4 b1 = *(const float4*)&scb[k * 256 + ty * 8 + 4];
            float a[16] = {t0.x,t0.y,t0.z,t0.w, t1.x,t1.y,t1.z,t1.w,
                           t2.x,t2.y,t2.z,t2.w, t3.x,t3.y,t3.z,t3.w};
            float bb[8] = {b0.x,b0.y,b0.z,b0.w, b1.x,b1.y,b1.z,b1.w};
            #pragma unroll
            for (int i = 0; i < 16; ++i)
                #pragma unroll
                for (int j = 0; j < 8; ++j)
                    acc[i][j] = fmaf(a[i], bb[j], acc[i][j]);
        }
    }

    // all compute reads of LDS done (every wave passed s=15's loop); make LDS reusable
    __syncthreads();

    // epilogue: d = (xnorm - 2*acc) + cnorm (identical rounding to the reference),
    // fused per-i argmin over the 8 codes -> write straight into LDS reduction array.
    const float* cnorm = ws + WS_CNORM;
    const float* xnorm = ws + WS_XNORM;
    float cn[8];
    #pragma unroll
    for (int j = 0; j < 8; ++j) cn[j] = cnorm[n0 + ty * 8 + j];
    float* red_d = &s_cb[0][0];           // [32 groups][128 pix] transposed
    int*   red_i = (int*)&s_cb[1][0];
    #pragma unroll
    for (int i = 0; i < 16; ++i) {
        int pix = (tx + (i >> 2) * 8) * 4 + (i & 3);   // permuted pixel mapping
        float x  = xnorm[P0 + pix];
        float bd = FLT_BIG; int bi = 0;
        #pragma unroll
        for (int j = 0; j < 8; ++j) {
            float t1 = x - 2.0f * acc[i][j];   // 2*acc exact
            float d  = t1 + cn[j];
            if (d < bd) { bd = d; bi = ty * 8 + j; }   // j ascending: lowest idx on tie
        }
        red_d[ty * 128 + pix] = bd;
        red_i[ty * 128 + pix] = bi;
    }
    __syncthreads();
    if (tid < 128) {
        float bd = FLT_BIG; int bi = 0;
        #pragma unroll 8
        for (int t = 0; t < 32; ++t) {       // t ascending = code ascending
            float d = red_d[t * 128 + tid];
            int   n = red_i[t * 128 + tid];
            if (d < bd) { bd = d; bi = n; }  // strict <: lowest idx on tie
        }
        // packed (d, idx): min over u64 = lexicographic (d asc, idx asc); d >= 0
        unsigned long long key =
            ((unsigned long long)__float_as_uint(bd) << 32) | (unsigned)(n0 + bi);
        atomicMin(&keys[P0 + tid], key);
    }
}

// ---------------- outputs: u copy, z_q gather, idx, loss partial sums ----------------
__global__ __launch_bounds__(256) void k_out(const float* __restrict__ u,
                                             const float* __restrict__ cb,
                                             const unsigned long long* __restrict__ keys,
                                             float* __restrict__ out,
                                             double* __restrict__ accum) {
    int P0   = blockIdx.x * 64;
    int b    = P0 >> 10;
    int hw0  = P0 & 1023;
    int lane = threadIdx.x & 63;
    int grp  = threadIdx.x >> 6;
    int p    = P0 + lane;
    unsigned long long key = keys[p];
    int idx  = (int)(unsigned int)(key & 0xffffffffull);
    const float* ub    = u + (size_t)b * (CHN * HWSZ) + hw0 + lane;
    float*       o0    = out + OUT_U  + (size_t)b * (CHN * HWSZ) + hw0 + lane;
    float*       o1    = out + OUT_ZT + (size_t)b * (CHN * HWSZ) + hw0 + lane;
    const float* cbrow = cb + (size_t)idx * CHN;
    float s = 0.f;
    #pragma unroll
    for (int r = 0; r < 8; ++r) {
        int c0 = grp * 8 + r * 32;
        float4 z0 = *(const float4*)&cbrow[c0];
        float4 z1 = *(const float4*)&cbrow[c0 + 4];
        float zq[8] = {z0.x,z0.y,z0.z,z0.w, z1.x,z1.y,z1.z,z1.w};
        #pragma unroll
        for (int cc = 0; cc < 8; ++cc) {
            int c = c0 + cc;
            float uv = ub[(size_t)c * HWSZ];
            float zv = zq[cc];
            o0[(size_t)c * HWSZ] = uv;
            o1[(size_t)c * HWSZ] = zv;
            float df = zv - uv;
            s = fmaf(df, df, s);
        }
    }
    #pragma unroll
    for (int off = 32; off > 0; off >>= 1) s += __shfl_down(s, off, 64);
    __shared__ float ls[4];
    if (lane == 0) ls[grp] = s;
    __syncthreads();
    if (threadIdx.x == 0) {
        float tot = (ls[0] + ls[1]) + (ls[2] + ls[3]);
        atomicAdd(accum, (double)tot);
    }
    if (grp == 0) out[OUT_IDX + p] = (float)idx;
}

// ---------------- finalize scalar loss ----------------
__global__ void k_loss(const double* __restrict__ accum,
                       float* __restrict__ out_loss) {
    float m = (float)(*accum / (double)NELEM);
    out_loss[0] = m + 0.25f * m;
}

extern "C" void kernel_launch(void* const* d_in, const int* in_sizes, int n_in,
                              void* d_out, int out_size, void* d_ws, size_t ws_size,
                              hipStream_t stream) {
    const float* u  = (const float*)d_in[0];
    const float* cb = (const float*)d_in[1];
    float* out = (float*)d_out;
    float* ws  = (float*)d_ws;

    k_prep  <<<dim3(NEMB + NPIX / 64), dim3(256), 0, stream>>>(cb, u, ws);
    k_argmin<<<dim3(1024),             dim3(256), 0, stream>>>(u, ws,
                 (unsigned long long*)(ws + WS_KEYS));
    k_out   <<<dim3(NPIX / 64),        dim3(256), 0, stream>>>(u, cb,
                 (const unsigned long long*)(ws + WS_KEYS), out,
                 (double*)(ws + WS_ACCUM));
    k_loss  <<<dim3(1),                dim3(1),   0, stream>>>(
                 (const double*)(ws + WS_ACCUM), out + OUT_LOSS);
}

// Round 5
// 293.639 us; speedup vs baseline: 2.7929x; 2.7929x over previous
//
#include <hip/hip_runtime.h>
#include <hip/hip_bf16.h>

#define BATCH 32
#define CHN   256
#define HWSZ  1024            // 32*32
#define NPIX  32768           // BATCH*HWSZ
#define NEMB  1024
#define NELEM 8388608         // BATCH*CHN*HWSZ
#define FLT_BIG 3.402823466e+38f
#define KCH   16              // K chunk per stage

// workspace layout (float offsets)
#define WS_CBT   0            // transposed codebook [256][1024]
#define WS_CNORM 262144       // 1024 floats
#define WS_XNORM 263168       // 32768 floats
#define WS_KEYS  296192       // 32768 u64 keys (65536 floats), 8B aligned
#define WS_ACCUM 361728       // 1 double, 8B aligned

// output layout (float offsets)
#define OUT_U    0
#define OUT_ZT   8388608
#define OUT_LOSS 16777216
#define OUT_IDX  16777217

// async global->LDS, 16B per lane. LDS dest must be lane-linear (base + lane*16).
__device__ __forceinline__ void gld_lds16(const float* g, float* lds) {
    __builtin_amdgcn_global_load_lds(
        (const __attribute__((address_space(1))) void*)g,
        (__attribute__((address_space(3))) void*)lds, 16, 0, 0);
}

// ---------------- prep: cb transpose + cnorm | xnorm + keys init + accum ----------------
__global__ __launch_bounds__(256) void k_prep(const float* __restrict__ cb,
                                              const float* __restrict__ u,
                                              float* __restrict__ ws) {
    int bid = blockIdx.x;
    if (bid < NEMB) {
        int n = bid;                 // code id
        int c = threadIdx.x;         // channel
        float v = cb[(size_t)n * CHN + c];
        ws[WS_CBT + (size_t)c * NEMB + n] = v;
        float s = v * v;
        #pragma unroll
        for (int off = 32; off > 0; off >>= 1) s += __shfl_down(s, off, 64);
        __shared__ float ls[4];
        if ((threadIdx.x & 63) == 0) ls[threadIdx.x >> 6] = s;
        __syncthreads();
        if (threadIdx.x == 0) ws[WS_CNORM + n] = (ls[0] + ls[1]) + (ls[2] + ls[3]);
    } else {
        int pb  = bid - NEMB;        // 0..511
        int P0  = pb * 64;
        int b   = P0 >> 10;
        int hw0 = P0 & 1023;
        int lane = threadIdx.x & 63;
        int grp  = threadIdx.x >> 6; // channel quarter
        const float* up = u + (size_t)b * (CHN * HWSZ) + hw0 + lane;
        float s = 0.f;
        #pragma unroll 8
        for (int c = 0; c < 64; ++c) {
            float v = up[(size_t)(grp * 64 + c) * HWSZ];
            s = fmaf(v, v, s);
        }
        __shared__ float ls2[4][64];
        ls2[grp][lane] = s;
        __syncthreads();
        if (grp == 0)
            ws[WS_XNORM + P0 + lane] =
                (ls2[0][lane] + ls2[1][lane]) + (ls2[2][lane] + ls2[3][lane]);
        if (threadIdx.x < 64)
            ((unsigned long long*)(ws + WS_KEYS))[P0 + threadIdx.x] = ~0ULL;
        if (pb == 0 && threadIdx.x == 0) *(double*)&ws[WS_ACCUM] = 0.0;
    }
}

// ---------------- main: distance GEMM + argmin ----------------
// Grid 512 = 256 pixel-blocks x 2 code-halves. Block: 256 thr, 128 px x 512 codes
// (2 nt iterations of 256 codes). Per-thread 16 px x 8 codes: 6 conflict-free
// ds_read_b128 per 128 FMA. K-chunk 16, double-buffered gld_lds staging.
// LDS 48KB dbuf + 32KB reduce = 80KB -> 2 blocks/CU. launch_bounds(256,2):
// VGPR cap 256 (acc 128 + frags + addr ~190 fits; (256,3)'s 168 cap spilled).
__global__ __launch_bounds__(256, 2) void k_argmin(const float* __restrict__ u,
                                                   const float* __restrict__ ws,
                                                   unsigned long long* __restrict__ keys) {
    __shared__ float s_u[2][KCH * 128];     // 16 KB  (16B slot q: k=q>>5, p4=q&31)
    __shared__ float s_cb[2][KCH * 256];    // 32 KB  (16B slot q: k=q>>6, j4=q&63)
    __shared__ float red_d[32 * 128];       // 16 KB  [ty][pix]
    __shared__ int   red_i[32 * 128];       // 16 KB

    const float* cbT = ws + WS_CBT;
    int bid  = blockIdx.x;
    int pb   = bid >> 1;
    int part = bid & 1;
    int P0   = pb * 128;
    int b    = P0 >> 10;
    int hw0  = P0 & 1023;
    int tid  = threadIdx.x;
    int tx   = tid & 7;                 // pixel group (16 px: quads tx, tx+8, tx+16, tx+24)
    int ty   = tid >> 3;                // code group (8 codes)
    const float* ub = u + (size_t)b * (CHN * HWSZ) + hw0;

    // stage g: nt = g>>4, kc = g&15. chunk = 16 k-rows of A(128 px) and B(256 codes).
    auto stage = [&](int g, int buf) {
        int c0  = (g & 15) * KCH;
        int n0g = part * 512 + (g >> 4) * 256;
        float* su  = &s_u[buf][0];
        float* scb = &s_cb[buf][0];
        #pragma unroll
        for (int it = 0; it < 2; ++it) {          // A: 512 slots
            int q = it * 256 + tid;
            gld_lds16(&ub[(size_t)(c0 + (q >> 5)) * HWSZ + (q & 31) * 4], &su[q * 4]);
        }
        #pragma unroll
        for (int it = 0; it < 4; ++it) {          // B: 1024 slots
            int q = it * 256 + tid;
            gld_lds16(&cbT[(size_t)(c0 + (q >> 6)) * NEMB + n0g + (q & 63) * 4],
                      &scb[q * 4]);
        }
    };

    stage(0, 0);

    for (int nt = 0; nt < 2; ++nt) {
        int n0 = part * 512 + nt * 256;
        float acc[16][8];
        #pragma unroll
        for (int i = 0; i < 16; ++i)
            #pragma unroll
            for (int j = 0; j < 8; ++j) acc[i][j] = 0.f;

        for (int s = 0; s < 16; ++s) {
            int g   = nt * 16 + s;
            int buf = g & 1;
            __syncthreads();                      // chunk g resident
            if (g < 31) stage(g + 1, buf ^ 1);    // prefetch next chunk
            const float* su  = &s_u[buf][0];
            const float* scb = &s_cb[buf][0];
            #pragma unroll 8
            for (int k = 0; k < KCH; ++k) {
                float4 t0 = *(const float4*)&su[(k * 32 + tx     ) * 4];
                float4 t1 = *(const float4*)&su[(k * 32 + tx +  8) * 4];
                float4 t2 = *(const float4*)&su[(k * 32 + tx + 16) * 4];
                float4 t3 = *(const float4*)&su[(k * 32 + tx + 24) * 4];
                float4 b0 = *(const float4*)&scb[k * 256 + ty * 8];
                float4 b1 = *(const float4*)&scb[k * 256 + ty * 8 + 4];
                float a_[16] = {t0.x,t0.y,t0.z,t0.w, t1.x,t1.y,t1.z,t1.w,
                                t2.x,t2.y,t2.z,t2.w, t3.x,t3.y,t3.z,t3.w};
                float b_[8]  = {b0.x,b0.y,b0.z,b0.w, b1.x,b1.y,b1.z,b1.w};
                #pragma unroll
                for (int i = 0; i < 16; ++i)
                    #pragma unroll
                    for (int j = 0; j < 8; ++j)
                        acc[i][j] = fmaf(a_[i], b_[j], acc[i][j]);
            }
        }

        // per-nt epilogue: d = (xnorm - 2*acc) + cnorm (reference rounding),
        // per-thread best-of-8, LDS cross-ty reduce, atomicMin merge.
        const float* cnorm = ws + WS_CNORM;
        const float* xnorm = ws + WS_XNORM;
        float cn[8];
        #pragma unroll
        for (int j = 0; j < 8; ++j) cn[j] = cnorm[n0 + ty * 8 + j];

        __syncthreads();   // waves done with prev red usage / k-loop of this nt
        #pragma unroll
        for (int t = 0; t < 4; ++t) {
            int p4 = tx + t * 8;                  // pixel quad
            float bd[4]; int bi[4];
            #pragma unroll
            for (int e = 0; e < 4; ++e) {
                int   i = t * 4 + e;
                float x = xnorm[P0 + p4 * 4 + e];
                float d0 = FLT_BIG; int i0 = 0;
                #pragma unroll
                for (int j = 0; j < 8; ++j) {
                    float t1 = x - 2.0f * acc[i][j];   // 2*acc exact
                    float d  = t1 + cn[j];
                    if (d < d0) { d0 = d; i0 = ty * 8 + j; }  // j asc: lowest idx tie
                }
                bd[e] = d0; bi[e] = i0;
            }
            *(float4*)&red_d[ty * 128 + p4 * 4] = make_float4(bd[0], bd[1], bd[2], bd[3]);
            *(int4*)  &red_i[ty * 128 + p4 * 4] = make_int4(bi[0], bi[1], bi[2], bi[3]);
        }
        __syncthreads();
        if (tid < 128) {
            float bd = FLT_BIG; int bi = 0;
            #pragma unroll 8
            for (int t = 0; t < 32; ++t) {        // t asc = code asc
                float d = red_d[t * 128 + tid];
                int   n = red_i[t * 128 + tid];
                if (d < bd) { bd = d; bi = n; }   // strict <: lowest idx on tie
            }
            unsigned long long key =
                ((unsigned long long)__float_as_uint(bd) << 32) | (unsigned)(n0 + bi);
            atomicMin(&keys[P0 + tid], key);
        }
    }
}

// ---------------- outputs: u copy, z_q gather, idx, loss partial sums ----------------
__global__ __launch_bounds__(256) void k_out(const float* __restrict__ u,
                                             const float* __restrict__ cb,
                                             const unsigned long long* __restrict__ keys,
                                             float* __restrict__ out,
                                             double* __restrict__ accum) {
    int P0   = blockIdx.x * 64;
    int b    = P0 >> 10;
    int hw0  = P0 & 1023;
    int lane = threadIdx.x & 63;
    int grp  = threadIdx.x >> 6;
    int p    = P0 + lane;
    unsigned long long key = keys[p];
    int idx  = (int)(unsigned int)(key & 0xffffffffull);
    const float* ub    = u + (size_t)b * (CHN * HWSZ) + hw0 + lane;
    float*       o0    = out + OUT_U  + (size_t)b * (CHN * HWSZ) + hw0 + lane;
    float*       o1    = out + OUT_ZT + (size_t)b * (CHN * HWSZ) + hw0 + lane;
    const float* cbrow = cb + (size_t)idx * CHN;
    float s = 0.f;
    #pragma unroll
    for (int r = 0; r < 8; ++r) {
        int c0 = grp * 8 + r * 32;
        float4 z0 = *(const float4*)&cbrow[c0];
        float4 z1 = *(const float4*)&cbrow[c0 + 4];
        float zq[8] = {z0.x,z0.y,z0.z,z0.w, z1.x,z1.y,z1.z,z1.w};
        #pragma unroll
        for (int cc = 0; cc < 8; ++cc) {
            int c = c0 + cc;
            float uv = ub[(size_t)c * HWSZ];
            float zv = zq[cc];
            o0[(size_t)c * HWSZ] = uv;
            o1[(size_t)c * HWSZ] = zv;
            float df = zv - uv;
            s = fmaf(df, df, s);
        }
    }
    #pragma unroll
    for (int off = 32; off > 0; off >>= 1) s += __shfl_down(s, off, 64);
    __shared__ float ls[4];
    if (lane == 0) ls[grp] = s;
    __syncthreads();
    if (threadIdx.x == 0) {
        float tot = (ls[0] + ls[1]) + (ls[2] + ls[3]);
        atomicAdd(accum, (double)tot);
    }
    if (grp == 0) out[OUT_IDX + p] = (float)idx;
}

// ---------------- finalize scalar loss ----------------
__global__ void k_loss(const double* __restrict__ accum,
                       float* __restrict__ out_loss) {
    float m = (float)(*accum / (double)NELEM);
    out_loss[0] = m + 0.25f * m;
}

extern "C" void kernel_launch(void* const* d_in, const int* in_sizes, int n_in,
                              void* d_out, int out_size, void* d_ws, size_t ws_size,
                              hipStream_t stream) {
    const float* u  = (const float*)d_in[0];
    const float* cb = (const float*)d_in[1];
    float* out = (float*)d_out;
    float* ws  = (float*)d_ws;

    k_prep  <<<dim3(NEMB + NPIX / 64), dim3(256), 0, stream>>>(cb, u, ws);
    k_argmin<<<dim3(512),              dim3(256), 0, stream>>>(u, ws,
                 (unsigned long long*)(ws + WS_KEYS));
    k_out   <<<dim3(NPIX / 64),        dim3(256), 0, stream>>>(u, cb,
                 (const unsigned long long*)(ws + WS_KEYS), out,
                 (double*)(ws + WS_ACCUM));
    k_loss  <<<dim3(1),                dim3(1),   0, stream>>>(
                 (const double*)(ws + WS_ACCUM), out + OUT_LOSS);
}